// Round 7
// baseline (301.430 us; speedup 1.0000x reference)
//
#include <hip/hip_runtime.h>
#include <hip/hip_bf16.h>

typedef __hip_bfloat16 bf16;
typedef _Float16 f16;
typedef __attribute__((ext_vector_type(8))) short bf16x8;
typedef __attribute__((ext_vector_type(8))) _Float16 f16x8;
typedef __attribute__((ext_vector_type(2))) _Float16 f16x2;
typedef __attribute__((ext_vector_type(4))) float f32x4;
typedef __attribute__((ext_vector_type(4))) unsigned int u32x4;
typedef __attribute__((ext_vector_type(2))) unsigned int u32x2;

#define B_ 4
#define N_ 4096
#define C_ 256
#define H_ 4
#define D_ 64
#define KLN 0.18033688011112042f   /* 0.125 * log2(e): folded into Q */

#if __has_builtin(__builtin_amdgcn_exp2f)
#define EXP2(x) __builtin_amdgcn_exp2f(x)
#else
#define EXP2(x) exp2f(x)
#endif
#if __has_builtin(__builtin_amdgcn_rcpf)
#define RCP(x) __builtin_amdgcn_rcpf(x)
#else
#define RCP(x) (1.0f / (x))
#endif

// two fp32 -> packed bf16 pair (round-half-up)
__device__ inline unsigned int pk2(float a, float b) {
    unsigned int ua = __builtin_bit_cast(unsigned int, a) + 0x8000u;
    unsigned int ub = __builtin_bit_cast(unsigned int, b) + 0x8000u;
    return (ua >> 16) | (ub & 0xffff0000u);
}
// two fp32 -> packed f16 pair (single v_cvt_pkrtz_f16_f32)
__device__ inline unsigned int pkh2(float a, float b) {
#if __has_builtin(__builtin_amdgcn_cvt_pkrtz)
    return __builtin_bit_cast(unsigned int, __builtin_amdgcn_cvt_pkrtz(a, b));
#else
    f16x2 h = { (f16)a, (f16)b };
    return __builtin_bit_cast(unsigned int, h);
#endif
}
// 8 contiguous fp32 -> bf16x8 fragment (pk2-based, 12 VALU)
__device__ inline bf16x8 cvt8(const float* __restrict__ p) {
    f32x4 a = *reinterpret_cast<const f32x4*>(p);
    f32x4 b = *reinterpret_cast<const f32x4*>(p + 4);
    u32x4 r = { pk2(a[0], a[1]), pk2(a[2], a[3]), pk2(b[0], b[1]), pk2(b[2], b[3]) };
    return __builtin_bit_cast(bf16x8, r);
}

// ---------------------------------------------------------------------------
// QKV projection (fp32 in, cast fused into staging / A-frag load).
// Block: 64 m-rows x 64 outputs; W slice staged fp32->bf16 in LDS.
// Q -> row-major [B,H,N,D], pre-scaled by KLN.
// K -> fragment-tiled [bh][n/16][d/32][ (d>>3)&3 ][n&15][d&7]   (1 KB frag = 1 coalesced b128/lane)
// V -> fragment-tiled f16 [bh][n/64][d/16][ (n>>5)&1 ][ (n>>3)&3 ][d&15][n&7]
// ---------------------------------------------------------------------------
__global__ __launch_bounds__(256, 2) void qkv_fused(const float* __restrict__ x,
                                                    const float* __restrict__ w,
                                                    bf16* __restrict__ qw,
                                                    bf16* __restrict__ kw,
                                                    f16* __restrict__ vtw)
{
    __shared__ short w_s[64][264];
    const int tid  = threadIdx.x;
    const int lane = tid & 63;
    const int wav  = tid >> 6;
    const int quad = lane >> 4;
    const int l16  = lane & 15;
    const int mt = blockIdx.x & 255, nb = blockIdx.x >> 8;
    const int m0 = mt * 64, n0 = nb * 64;

    {   // stage W slice [n0..n0+63][0..255], fp32 -> bf16
        const int row = tid >> 2, cb = (tid & 3) * 64;
        const float* src = w + (size_t)(n0 + row) * C_ + cb;
#pragma unroll
        for (int i = 0; i < 8; ++i) {
            f32x4 a = *reinterpret_cast<const f32x4*>(src + i * 8);
            f32x4 b = *reinterpret_cast<const f32x4*>(src + i * 8 + 4);
            u32x4 pkd = { pk2(a[0], a[1]), pk2(a[2], a[3]),
                          pk2(b[0], b[1]), pk2(b[2], b[3]) };
            *reinterpret_cast<u32x4*>(&w_s[row][cb + i * 8]) = pkd;
        }
    }
    __syncthreads();

    f32x4 acc[4] = {{0,0,0,0},{0,0,0,0},{0,0,0,0},{0,0,0,0}};
    const float* xrow = x + (size_t)(m0 + wav * 16 + l16) * C_ + quad * 8;
#pragma unroll
    for (int k0 = 0; k0 < C_; k0 += 32) {
        bf16x8 a = cvt8(xrow + k0);
#pragma unroll
        for (int nt = 0; nt < 4; ++nt) {
            bf16x8 b = *reinterpret_cast<const bf16x8*>(&w_s[nt * 16 + l16][k0 + quad * 8]);
            acc[nt] = __builtin_amdgcn_mfma_f32_16x16x32_bf16(a, b, acc[nt], 0, 0, 0);
        }
    }

    const int bb = m0 >> 12;
    const int nbase = (m0 + wav * 16) & (N_ - 1);
    if (nb < 4) {                            // Q row-major, scaled
        const int h = nb;
#pragma unroll
        for (int nt = 0; nt < 4; ++nt)
#pragma unroll
            for (int r = 0; r < 4; ++r) {
                int n = nbase + quad * 4 + r, d = nt * 16 + l16;
                qw[(((size_t)bb * H_ + h) * N_ + n) * D_ + d] =
                    __float2bfloat16(acc[nt][r] * KLN);
            }
    } else if (nb < 8) {                     // K fragment-tiled
        const int h = nb - 4;
        bf16* kb_ = kw + (size_t)(bb * H_ + h) * (N_ / 16) * 1024;
        const int jblk = nbase >> 4;
#pragma unroll
        for (int nt = 0; nt < 4; ++nt) {
            const int base = jblk * 1024 + (nt >> 1) * 512 +
                             (((nt * 2) + (l16 >> 3)) & 3) * 128 + (l16 & 7);
#pragma unroll
            for (int r = 0; r < 4; ++r)
                kb_[base + (quad * 4 + r) * 8] = __float2bfloat16(acc[nt][r]);
        }
    } else {                                 // V fragment-tiled f16
        const int h = nb - 8;
        f16* vb_ = vtw + (size_t)(bb * H_ + h) * (N_ / 64) * 4096;
        const int jblk64 = nbase >> 6;
        const int ksv    = (nbase >> 5) & 1;
        const int quadv  = (((nbase & 31) + quad * 4) >> 3) & 3;
        const int ev     = (quad & 1) * 4;
#pragma unroll
        for (int nt = 0; nt < 4; ++nt) {
            u32x2 wv = { pkh2(acc[nt][0], acc[nt][1]), pkh2(acc[nt][2], acc[nt][3]) };
            *reinterpret_cast<u32x2*>(
                &vb_[jblk64 * 4096 + nt * 1024 + ksv * 512 + (quadv * 16 + l16) * 8 + ev]) = wv;
        }
    }
}

// ---------------------------------------------------------------------------
// Flash attention v5: barrier-free main loop.
// Wave = 64 q-rows x one j-half (2048). K/V fragments loaded DIRECTLY from
// the pre-tiled global layouts (each = one coalesced b128/lane, L2-resident);
// K double-buffered in registers, V loaded at tile top. LDS only for the
// same-wave P^T round-trip (36 KB) + final j-half merge (2 barriers total).
// No-max softmax (Q pre-scaled); l accumulated in VALU (per-quad partial,
// cross-quad reduced once at the end).
// ---------------------------------------------------------------------------
__global__ __launch_bounds__(256, 2) void attn(const bf16* __restrict__ q,
                                               const bf16* __restrict__ kt,
                                               const f16* __restrict__ vt,
                                               bf16* __restrict__ o)
{
    __shared__ unsigned int p_s[4][64 * 36];     // per-wave P^T; reused as merge buf

    const int tid  = threadIdx.x;
    const int lane = tid & 63;
    const int wav  = tid >> 6;
    const int quad = lane >> 4;
    const int l16  = lane & 15;
    const int sub  = wav & 1;        // q-subtile (64 rows)
    const int jh   = wav >> 1;       // j-half
    // XCD-grouping: same bh lands on same XCD (bid%8 heuristic)
    const int bh = (blockIdx.x & 7) | (((blockIdx.x >> 3) & 1) << 3);
    const int qt = blockIdx.x >> 4;  // 0..31
    const int bb = bh >> 2, h = bh & 3;

    const bf16* qp  = q  + (size_t)bh * N_ * D_;
    const bf16* ktp = kt + (size_t)bh * (N_ / 16) * 1024 + lane * 8;
    const f16*  vtp = vt + (size_t)bh * (N_ / 64) * 4096 + lane * 8;

    const int qbase = qt * 128 + sub * 64;
    bf16x8 qb[4][2];
#pragma unroll
    for (int qg = 0; qg < 4; ++qg)
#pragma unroll
        for (int ks = 0; ks < 2; ++ks)
            qb[qg][ks] = *reinterpret_cast<const bf16x8*>(
                qp + (size_t)(qbase + qg * 16 + l16) * D_ + ks * 32 + quad * 8);

    f32x4 oacc[4][4];
#pragma unroll
    for (int qg = 0; qg < 4; ++qg)
#pragma unroll
        for (int dt = 0; dt < 4; ++dt) oacc[qg][dt] = (f32x4){0,0,0,0};
    float lsum[4] = {0.f, 0.f, 0.f, 0.f};

    bf16x8 kA[4][2], kB[4][2];
    {   // initial K tile (t=0) for this j-half
        const int jb0 = (jh * 2048) >> 4;
#pragma unroll
        for (int nt = 0; nt < 4; ++nt)
#pragma unroll
            for (int ks = 0; ks < 2; ++ks)
                kA[nt][ks] = *reinterpret_cast<const bf16x8*>(
                    ktp + (size_t)(jb0 + nt) * 1024 + ks * 512);
    }

    auto tile = [&](bf16x8 (&kc)[4][2], bf16x8 (&kn)[4][2], int t) {
        // V for this tile (used after QK+softmax ~350 cyc later)
        f16x8 va[2][4];
#pragma unroll
        for (int ks = 0; ks < 2; ++ks)
#pragma unroll
            for (int dt = 0; dt < 4; ++dt)
                va[ks][dt] = *reinterpret_cast<const f16x8*>(
                    vtp + (size_t)(jh * 32 + t) * 4096 + dt * 1024 + ks * 512);
        // K prefetch for t+1
        if (t < 31) {
            const int jbn = ((jh * 2048 + (t + 1) * 64) >> 4);
#pragma unroll
            for (int nt = 0; nt < 4; ++nt)
#pragma unroll
                for (int ks = 0; ks < 2; ++ks)
                    kn[nt][ks] = *reinterpret_cast<const bf16x8*>(
                        ktp + (size_t)(jbn + nt) * 1024 + ks * 512);
        }
        // S^T = K·Q^T per q-group; p = exp2(s); l += p; pack f16 -> p_s
#pragma unroll
        for (int qg = 0; qg < 4; ++qg) {
            f32x4 s[4] = {{0,0,0,0},{0,0,0,0},{0,0,0,0},{0,0,0,0}};
#pragma unroll
            for (int nt = 0; nt < 4; ++nt) {
                s[nt] = __builtin_amdgcn_mfma_f32_16x16x32_bf16(kc[nt][0], qb[qg][0], s[nt], 0, 0, 0);
                s[nt] = __builtin_amdgcn_mfma_f32_16x16x32_bf16(kc[nt][1], qb[qg][1], s[nt], 0, 0, 0);
            }
            unsigned int* prow = &p_s[wav][(qg * 16 + l16) * 36];
            float lq = 0.f;
#pragma unroll
            for (int nt = 0; nt < 4; ++nt) {
                float p0 = EXP2(s[nt][0]);
                float p1 = EXP2(s[nt][1]);
                float p2 = EXP2(s[nt][2]);
                float p3 = EXP2(s[nt][3]);
                lq += (p0 + p1) + (p2 + p3);
                u32x2 w2 = { pkh2(p0, p1), pkh2(p2, p3) };
                *reinterpret_cast<u32x2*>(prow + nt * 8 + quad * 2) = w2;
            }
            lsum[qg] += lq;
        }
        asm volatile("" ::: "memory");   // pin same-wave DS write->read order

        // O^T += V^T·P^T
#pragma unroll
        for (int ks = 0; ks < 2; ++ks) {
            f16x8 pb[4];
#pragma unroll
            for (int qg = 0; qg < 4; ++qg) {
                u32x4 pw = *reinterpret_cast<const u32x4*>(
                    &p_s[wav][(qg * 16 + l16) * 36 + ks * 16 + quad * 4]);
                pb[qg] = __builtin_bit_cast(f16x8, pw);
            }
#pragma unroll
            for (int dt = 0; dt < 4; ++dt)
#pragma unroll
                for (int qg = 0; qg < 4; ++qg)
                    oacc[qg][dt] = __builtin_amdgcn_mfma_f32_16x16x32_f16(va[ks][dt], pb[qg], oacc[qg][dt], 0, 0, 0);
        }
    };

    for (int t = 0; t < 32; t += 2) {
        tile(kA, kB, t);
        tile(kB, kA, t + 1);
    }

    // cross-quad completion of l (per-lane per-quad partials -> full row sums)
#pragma unroll
    for (int qg = 0; qg < 4; ++qg) {
        lsum[qg] += __shfl_xor(lsum[qg], 16, 64);
        lsum[qg] += __shfl_xor(lsum[qg], 32, 64);
    }

    // ---- merge j-halves (exact: O and l add), then normalize + store ----
    __syncthreads();                  // all p_s reads done; reuse as merge buffer
    float* mrg = reinterpret_cast<float*>(p_s);
    if (jh == 1) {
        float* dst = mrg + (sub * 64 + lane) * 68;
#pragma unroll
        for (int qg = 0; qg < 4; ++qg) {
#pragma unroll
            for (int dt = 0; dt < 4; ++dt)
#pragma unroll
                for (int e = 0; e < 4; ++e)
                    dst[qg * 17 + dt * 4 + e] = oacc[qg][dt][e];
            dst[qg * 17 + 16] = lsum[qg];
        }
    }
    __syncthreads();
    if (jh == 0) {
        const float* src = mrg + (sub * 64 + lane) * 68;
#pragma unroll
        for (int qg = 0; qg < 4; ++qg) {
            float rl = RCP(lsum[qg] + src[qg * 17 + 16]);
            const size_t obase = ((size_t)bb * N_ + qbase + qg * 16 + l16) * C_ + h * D_;
#pragma unroll
            for (int dt = 0; dt < 4; ++dt) {
                float v0 = (oacc[qg][dt][0] + src[qg * 17 + dt * 4 + 0]) * rl;
                float v1 = (oacc[qg][dt][1] + src[qg * 17 + dt * 4 + 1]) * rl;
                float v2 = (oacc[qg][dt][2] + src[qg * 17 + dt * 4 + 2]) * rl;
                float v3 = (oacc[qg][dt][3] + src[qg * 17 + dt * 4 + 3]) * rl;
                u32x2 wv = { pk2(v0, v1), pk2(v2, v3) };
                *reinterpret_cast<u32x2*>(o + obase + dt * 16 + quad * 4) = wv;
            }
        }
    }
}

// ---------------------------------------------------------------------------
// Output projection: W staged fp32->bf16 in LDS; bf16 A; fp32 out + bias.
// ---------------------------------------------------------------------------
__global__ __launch_bounds__(256, 2) void out_proj(const bf16* __restrict__ ov,
                                                   const float* __restrict__ w,
                                                   const float* __restrict__ bias,
                                                   float* __restrict__ out)
{
    __shared__ short w_s[64][264];
    const int tid  = threadIdx.x;
    const int lane = tid & 63;
    const int wav  = tid >> 6;
    const int quad = lane >> 4;
    const int l16  = lane & 15;
    const int m0 = (blockIdx.x >> 2) * 64;
    const int n0 = (blockIdx.x & 3) * 64;

    {
        const int row = tid >> 2, cb = (tid & 3) * 64;
        const float* src = w + (size_t)(n0 + row) * C_ + cb;
#pragma unroll
        for (int i = 0; i < 8; ++i) {
            f32x4 a = *reinterpret_cast<const f32x4*>(src + i * 8);
            f32x4 b = *reinterpret_cast<const f32x4*>(src + i * 8 + 4);
            u32x4 pkd = { pk2(a[0], a[1]), pk2(a[2], a[3]),
                          pk2(b[0], b[1]), pk2(b[2], b[3]) };
            *reinterpret_cast<u32x4*>(&w_s[row][cb + i * 8]) = pkd;
        }
    }
    __syncthreads();

    f32x4 acc[4] = {{0,0,0,0},{0,0,0,0},{0,0,0,0},{0,0,0,0}};
    const bf16* orow = ov + (size_t)(m0 + wav * 16 + l16) * C_ + quad * 8;
#pragma unroll
    for (int k0 = 0; k0 < C_; k0 += 32) {
        bf16x8 a = *reinterpret_cast<const bf16x8*>(orow + k0);
#pragma unroll
        for (int nt = 0; nt < 4; ++nt) {
            bf16x8 b = *reinterpret_cast<const bf16x8*>(&w_s[nt * 16 + l16][k0 + quad * 8]);
            acc[nt] = __builtin_amdgcn_mfma_f32_16x16x32_bf16(a, b, acc[nt], 0, 0, 0);
        }
    }
#pragma unroll
    for (int nt = 0; nt < 4; ++nt)
#pragma unroll
        for (int r = 0; r < 4; ++r) {
            int m  = m0 + wav * 16 + quad * 4 + r;
            int oc = n0 + nt * 16 + l16;
            out[(size_t)m * C_ + oc] = acc[nt][r] + bias[oc];
        }
}

extern "C" void kernel_launch(void* const* d_in, const int* in_sizes, int n_in,
                              void* d_out, int out_size, void* d_ws, size_t ws_size,
                              hipStream_t stream) {
    const float* x      = (const float*)d_in[0];
    const float* w_qkv  = (const float*)d_in[1];
    const float* w_proj = (const float*)d_in[2];
    const float* b_proj = (const float*)d_in[3];
    float* out = (float*)d_out;

    const size_t qkv_elems = (size_t)B_ * H_ * N_ * D_;   // 4,194,304
    bf16* q_ws  = (bf16*)d_ws;
    bf16* k_ws  = q_ws + qkv_elems;
    f16*  vt_ws = (f16*)(k_ws + qkv_elems);
    bf16* o_ws  = (bf16*)(vt_ws + qkv_elems);             // total 32 MB

    qkv_fused<<<3072, 256, 0, stream>>>(x, w_qkv, q_ws, k_ws, vt_ws);
    attn     <<< 512, 256, 0, stream>>>(q_ws, k_ws, vt_ws, o_ws);
    out_proj <<<1024, 256, 0, stream>>>(o_ws, w_proj, b_proj, out);
}

// Round 8
// 284.333 us; speedup vs baseline: 1.0601x; 1.0601x over previous
//
#include <hip/hip_runtime.h>
#include <hip/hip_bf16.h>

typedef __hip_bfloat16 bf16;
typedef _Float16 f16;
typedef __attribute__((ext_vector_type(8))) short bf16x8;
typedef __attribute__((ext_vector_type(8))) _Float16 f16x8;
typedef __attribute__((ext_vector_type(2))) _Float16 f16x2;
typedef __attribute__((ext_vector_type(4))) float f32x4;
typedef __attribute__((ext_vector_type(4))) unsigned int u32x4;
typedef __attribute__((ext_vector_type(2))) unsigned int u32x2;

#define B_ 4
#define N_ 4096
#define C_ 256
#define H_ 4
#define D_ 64
#define KLN 0.18033688011112042f   /* 0.125 * log2(e): folded into Q */

#if __has_builtin(__builtin_amdgcn_exp2f)
#define EXP2(x) __builtin_amdgcn_exp2f(x)
#else
#define EXP2(x) exp2f(x)
#endif
#if __has_builtin(__builtin_amdgcn_rcpf)
#define RCP(x) __builtin_amdgcn_rcpf(x)
#else
#define RCP(x) (1.0f / (x))
#endif

// direct global->LDS DMA, 16B per lane. LDS dest = wave-uniform base + lane*16.
__device__ inline void load_lds16(const void* g, void* l) {
#if __has_builtin(__builtin_amdgcn_global_load_lds)
    __builtin_amdgcn_global_load_lds(
        (const __attribute__((address_space(1))) unsigned int*)g,
        (__attribute__((address_space(3))) unsigned int*)l, 16, 0, 0);
#else
    int ln = __lane_id();
    ((u32x4*)l)[ln] = *((const u32x4*)g);
#endif
}

// two fp32 -> packed bf16 pair (round-half-up)
__device__ inline unsigned int pk2(float a, float b) {
    unsigned int ua = __builtin_bit_cast(unsigned int, a) + 0x8000u;
    unsigned int ub = __builtin_bit_cast(unsigned int, b) + 0x8000u;
    return (ua >> 16) | (ub & 0xffff0000u);
}
// two fp32 -> packed f16 pair (single v_cvt_pkrtz_f16_f32)
__device__ inline unsigned int pkh2(float a, float b) {
#if __has_builtin(__builtin_amdgcn_cvt_pkrtz)
    return __builtin_bit_cast(unsigned int, __builtin_amdgcn_cvt_pkrtz(a, b));
#else
    f16x2 h = { (f16)a, (f16)b };
    return __builtin_bit_cast(unsigned int, h);
#endif
}

// ---------------------------------------------------------------------------
// Prep: cast x, w_qkv, w_proj fp32 -> bf16 (memory-bound).
// ---------------------------------------------------------------------------
__global__ __launch_bounds__(256) void cast_bf16(const float* __restrict__ x,
                                                 const float* __restrict__ wq,
                                                 const float* __restrict__ wp,
                                                 bf16* __restrict__ xb,
                                                 bf16* __restrict__ wqb,
                                                 bf16* __restrict__ wpb)
{
    int bid = blockIdx.x;
    const float* s; bf16* d; int base;
    if (bid < 2048)      { s = x;  d = xb;  base = bid * 2048; }
    else if (bid < 2144) { s = wq; d = wqb; base = (bid - 2048) * 2048; }
    else                 { s = wp; d = wpb; base = (bid - 2144) * 2048; }
    int i = base + threadIdx.x * 8;
    f32x4 a = *reinterpret_cast<const f32x4*>(s + i);
    f32x4 b = *reinterpret_cast<const f32x4*>(s + i + 4);
    u32x4 o;
    o.x = pk2(a[0], a[1]); o.y = pk2(a[2], a[3]);
    o.z = pk2(b[0], b[1]); o.w = pk2(b[2], b[3]);
    *reinterpret_cast<u32x4*>(d + i) = o;
}

// ---------------------------------------------------------------------------
// QKV projection, bf16 in, W staged in LDS.
// Q -> row-major [B,H,N,D], pre-scaled by KLN.
// K -> FRAGMENT-TILED (round-7 layout): one coalesced b128/lane per fragment.
// V -> transposed row-major [B,H,D,N] f16 (staged via DMA in attn).
// ---------------------------------------------------------------------------
__global__ __launch_bounds__(256, 2) void qkv_fast(const bf16* __restrict__ x,
                                                   const bf16* __restrict__ w,
                                                   bf16* __restrict__ qw,
                                                   bf16* __restrict__ kw,
                                                   f16* __restrict__ vtw)
{
    __shared__ short w_s[64][264];
    const int tid  = threadIdx.x;
    const int lane = tid & 63;
    const int wav  = tid >> 6;
    const int quad = lane >> 4;
    const int l16  = lane & 15;
    const int mt = blockIdx.x / 12, nb = blockIdx.x % 12;
    const int m0 = mt * 64, n0 = nb * 64;

    {
        const int row = tid >> 2, cb = (tid & 3) * 64;
        const bf16* src = w + (size_t)(n0 + row) * C_ + cb;
#pragma unroll
        for (int i = 0; i < 8; ++i)
            *reinterpret_cast<bf16x8*>(&w_s[row][cb + i * 8]) =
                *reinterpret_cast<const bf16x8*>(src + i * 8);
    }
    __syncthreads();

    f32x4 acc[4] = {{0,0,0,0},{0,0,0,0},{0,0,0,0},{0,0,0,0}};
    const bf16* xrow = x + (size_t)(m0 + wav * 16 + l16) * C_ + quad * 8;
#pragma unroll
    for (int k0 = 0; k0 < C_; k0 += 32) {
        bf16x8 a = *reinterpret_cast<const bf16x8*>(xrow + k0);
#pragma unroll
        for (int nt = 0; nt < 4; ++nt) {
            bf16x8 b = *reinterpret_cast<const bf16x8*>(&w_s[nt * 16 + l16][k0 + quad * 8]);
            acc[nt] = __builtin_amdgcn_mfma_f32_16x16x32_bf16(a, b, acc[nt], 0, 0, 0);
        }
    }

    const int bb = m0 >> 12;
    const int nbase = (m0 + wav * 16) & (N_ - 1);
    if (nb < 4) {                            // Q row-major, scaled
        const int h = nb;
#pragma unroll
        for (int nt = 0; nt < 4; ++nt)
#pragma unroll
            for (int r = 0; r < 4; ++r) {
                int n = nbase + quad * 4 + r, d = nt * 16 + l16;
                qw[(((size_t)bb * H_ + h) * N_ + n) * D_ + d] =
                    __float2bfloat16(acc[nt][r] * KLN);
            }
    } else if (nb < 8) {                     // K fragment-tiled (round-7 layout)
        const int h = nb - 4;
        bf16* kb_ = kw + (size_t)(bb * H_ + h) * (N_ / 16) * 1024;
        const int jblk = nbase >> 4;
#pragma unroll
        for (int nt = 0; nt < 4; ++nt) {
            const int base = jblk * 1024 + (nt >> 1) * 512 +
                             (((nt * 2) + (l16 >> 3)) & 3) * 128 + (l16 & 7);
#pragma unroll
            for (int r = 0; r < 4; ++r)
                kb_[base + (quad * 4 + r) * 8] = __float2bfloat16(acc[nt][r]);
        }
    } else {                                 // V transposed row-major, f16
        const int h = nb - 8;
#pragma unroll
        for (int nt = 0; nt < 4; ++nt) {
            int d = nt * 16 + l16;
            u32x2 wv;
            wv.x = pkh2(acc[nt][0], acc[nt][1]);
            wv.y = pkh2(acc[nt][2], acc[nt][3]);
            *reinterpret_cast<u32x2*>(
                vtw + (((size_t)bb * H_ + h) * D_ + d) * N_ + nbase + quad * 4) = wv;
        }
    }
}

// ---------------------------------------------------------------------------
// Flash attention v6 (round-6 skeleton, audited register budget).
// Block = 4 waves = 2 q-subtiles x 2 j-halves; wave = 64 q-rows.
// K: register-direct, SINGLE-buffered, from the pre-tiled global layout
//    (one coalesced b128/lane; L2-resident; loads issued before the barriers
//    so their latency hides behind the V-DMA drain).
// V: global_load_lds into XOR-swizzled LDS tile (round-6 path).
// P: same-wave LDS round-trip. l: VALU accumulation (no ones-MFMA).
// LDS 52 KB + ~165 regs @ __launch_bounds__(256,3) -> 3 blocks/CU.
// ---------------------------------------------------------------------------
__global__ __launch_bounds__(256, 3) void attn(const bf16* __restrict__ q,
                                               const bf16* __restrict__ kt,
                                               const f16* __restrict__ vt,
                                               bf16* __restrict__ o)
{
    __shared__ f16          v_s[2][64 * 64];     // [jh][d*64 + slot*8], 16 KB
    __shared__ unsigned int p_s[4][64 * 36];     // per-wave P^T; merge buf; 36 KB

    const int tid  = threadIdx.x;
    const int lane = tid & 63;
    const int wav  = tid >> 6;
    const int quad = lane >> 4;
    const int l16  = lane & 15;
    const int l8   = l16 & 7;
    const int sub  = wav & 1;        // q-subtile (64 rows)
    const int jh   = wav >> 1;       // j-half
    const int bh = (blockIdx.x & 7) | (((blockIdx.x >> 3) & 1) << 3);  // XCD-grouped
    const int qt = blockIdx.x >> 4;  // 0..31
    const int bb = bh >> 2, h = bh & 3;

    const bf16* qp  = q  + (size_t)bh * N_ * D_;
    const bf16* ktp = kt + (size_t)bh * (N_ / 16) * 1024 + lane * 8;
    const f16*  vp  = vt + (size_t)bh * D_ * N_;

    const int qbase = qt * 128 + sub * 64;
    bf16x8 qb[4][2];
#pragma unroll
    for (int qg = 0; qg < 4; ++qg)
#pragma unroll
        for (int ks = 0; ks < 2; ++ks)
            qb[qg][ks] = *reinterpret_cast<const bf16x8*>(
                qp + (size_t)(qbase + qg * 16 + l16) * D_ + ks * 32 + quad * 8);

    // V staging geometry (XOR swizzle: slot = chunk ^ (row&7))
    const int ri = lane >> 3;
    const int ci = lane & 7;
    const int gc = ci ^ ri;

    f32x4 oacc[4][4];
#pragma unroll
    for (int qg = 0; qg < 4; ++qg)
#pragma unroll
        for (int dt = 0; dt < 4; ++dt) oacc[qg][dt] = (f32x4){0,0,0,0};
    float lsum[4] = {0.f, 0.f, 0.f, 0.f};

    for (int t = 0; t < 32; ++t) {
        const int j0 = jh * 2048 + t * 64;

        // K fragments for this tile: global->reg, issued BEFORE the barriers
        // (latency overlaps the barrier wait + V-DMA drain).
        bf16x8 kc[4][2];
        const int jbt = j0 >> 4;
#pragma unroll
        for (int nt = 0; nt < 4; ++nt)
#pragma unroll
            for (int ks = 0; ks < 2; ++ks)
                kc[nt][ks] = *reinterpret_cast<const bf16x8*>(
                    ktp + (size_t)(jbt + nt) * 1024 + ks * 512);

        __syncthreads();                        // prev tile's v_s reads done
#pragma unroll
        for (int g = 0; g < 4; ++g) {           // each wave stages 32 d-rows of V
            const int rl_ = sub * 32 + g * 8;
            load_lds16(vp + (size_t)(rl_ + ri) * N_ + j0 + gc * 8, &v_s[jh][rl_ * 64]);
        }
        __syncthreads();                        // vmcnt(0): v_s staged, kc arrived

        // S^T = K·Q^T per q-group; p = exp2(s); l += p; pack f16 -> p_s
#pragma unroll
        for (int qg = 0; qg < 4; ++qg) {
            f32x4 s[4] = {{0,0,0,0},{0,0,0,0},{0,0,0,0},{0,0,0,0}};
#pragma unroll
            for (int nt = 0; nt < 4; ++nt) {
                s[nt] = __builtin_amdgcn_mfma_f32_16x16x32_bf16(kc[nt][0], qb[qg][0], s[nt], 0, 0, 0);
                s[nt] = __builtin_amdgcn_mfma_f32_16x16x32_bf16(kc[nt][1], qb[qg][1], s[nt], 0, 0, 0);
            }
            unsigned int* prow = &p_s[wav][(qg * 16 + l16) * 36];
            float lq = 0.f;
#pragma unroll
            for (int nt = 0; nt < 4; ++nt) {
                float p0 = EXP2(s[nt][0]);
                float p1 = EXP2(s[nt][1]);
                float p2 = EXP2(s[nt][2]);
                float p3 = EXP2(s[nt][3]);
                lq += (p0 + p1) + (p2 + p3);
                u32x2 w2 = { pkh2(p0, p1), pkh2(p2, p3) };
                *reinterpret_cast<u32x2*>(prow + nt * 8 + quad * 2) = w2;
            }
            lsum[qg] += lq;
        }
        asm volatile("" ::: "memory");   // pin same-wave DS write->read order

        // O^T += V^T·P^T
#pragma unroll
        for (int ks = 0; ks < 2; ++ks) {
            f16x8 pb[4];
#pragma unroll
            for (int qg = 0; qg < 4; ++qg) {
                u32x4 pw = *reinterpret_cast<const u32x4*>(
                    &p_s[wav][(qg * 16 + l16) * 36 + ks * 16 + quad * 4]);
                pb[qg] = __builtin_bit_cast(f16x8, pw);
            }
#pragma unroll
            for (int dt = 0; dt < 4; ++dt) {
                f16x8 va = *reinterpret_cast<const f16x8*>(
                    &v_s[jh][(dt * 16 + l16) * 64 + (((ks << 2) + quad) ^ l8) * 8]);
#pragma unroll
                for (int qg = 0; qg < 4; ++qg)
                    oacc[qg][dt] = __builtin_amdgcn_mfma_f32_16x16x32_f16(va, pb[qg], oacc[qg][dt], 0, 0, 0);
            }
        }
    }

    // cross-quad completion of l
#pragma unroll
    for (int qg = 0; qg < 4; ++qg) {
        lsum[qg] += __shfl_xor(lsum[qg], 16, 64);
        lsum[qg] += __shfl_xor(lsum[qg], 32, 64);
    }

    // ---- merge j-halves (exact: O and l add), then normalize + store ----
    __syncthreads();
    float* mrg = reinterpret_cast<float*>(p_s);
    if (jh == 1) {
        float* dst = mrg + (sub * 64 + lane) * 68;
#pragma unroll
        for (int qg = 0; qg < 4; ++qg) {
#pragma unroll
            for (int dt = 0; dt < 4; ++dt)
#pragma unroll
                for (int e = 0; e < 4; ++e)
                    dst[qg * 17 + dt * 4 + e] = oacc[qg][dt][e];
            dst[qg * 17 + 16] = lsum[qg];
        }
    }
    __syncthreads();
    if (jh == 0) {
        const float* src = mrg + (sub * 64 + lane) * 68;
#pragma unroll
        for (int qg = 0; qg < 4; ++qg) {
            float rl = RCP(lsum[qg] + src[qg * 17 + 16]);
            const size_t obase = ((size_t)bb * N_ + qbase + qg * 16 + l16) * C_ + h * D_;
#pragma unroll
            for (int dt = 0; dt < 4; ++dt) {
                float v0 = (oacc[qg][dt][0] + src[qg * 17 + dt * 4 + 0]) * rl;
                float v1 = (oacc[qg][dt][1] + src[qg * 17 + dt * 4 + 1]) * rl;
                float v2 = (oacc[qg][dt][2] + src[qg * 17 + dt * 4 + 2]) * rl;
                float v3 = (oacc[qg][dt][3] + src[qg * 17 + dt * 4 + 3]) * rl;
                u32x2 wv = { pk2(v0, v1), pk2(v2, v3) };
                *reinterpret_cast<u32x2*>(o + obase + dt * 16 + quad * 4) = wv;
            }
        }
    }
}

// ---------------------------------------------------------------------------
// Output projection with W (bf16) staged in LDS; fp32 out + bias.
// ---------------------------------------------------------------------------
__global__ __launch_bounds__(256, 2) void out_proj_fast(const bf16* __restrict__ ov,
                                                        const bf16* __restrict__ w,
                                                        const float* __restrict__ bias,
                                                        float* __restrict__ out)
{
    __shared__ short w_s[64][264];
    const int tid  = threadIdx.x;
    const int lane = tid & 63;
    const int wav  = tid >> 6;
    const int quad = lane >> 4;
    const int l16  = lane & 15;
    const int m0 = (blockIdx.x >> 2) * 64;
    const int n0 = (blockIdx.x & 3) * 64;

    {
        const int row = tid >> 2, cb = (tid & 3) * 64;
        const bf16* src = w + (size_t)(n0 + row) * C_ + cb;
#pragma unroll
        for (int i = 0; i < 8; ++i)
            *reinterpret_cast<bf16x8*>(&w_s[row][cb + i * 8]) =
                *reinterpret_cast<const bf16x8*>(src + i * 8);
    }
    __syncthreads();

    f32x4 acc[4] = {{0,0,0,0},{0,0,0,0},{0,0,0,0},{0,0,0,0}};
    const bf16* orow = ov + (size_t)(m0 + wav * 16 + l16) * C_ + quad * 8;
#pragma unroll
    for (int k0 = 0; k0 < C_; k0 += 32) {
        bf16x8 a = *reinterpret_cast<const bf16x8*>(orow + k0);
#pragma unroll
        for (int nt = 0; nt < 4; ++nt) {
            bf16x8 b = *reinterpret_cast<const bf16x8*>(&w_s[nt * 16 + l16][k0 + quad * 8]);
            acc[nt] = __builtin_amdgcn_mfma_f32_16x16x32_bf16(a, b, acc[nt], 0, 0, 0);
        }
    }
#pragma unroll
    for (int nt = 0; nt < 4; ++nt)
#pragma unroll
        for (int r = 0; r < 4; ++r) {
            int m  = m0 + wav * 16 + quad * 4 + r;
            int oc = n0 + nt * 16 + l16;
            out[(size_t)m * C_ + oc] = acc[nt][r] + bias[oc];
        }
}

extern "C" void kernel_launch(void* const* d_in, const int* in_sizes, int n_in,
                              void* d_out, int out_size, void* d_ws, size_t ws_size,
                              hipStream_t stream) {
    const float* x      = (const float*)d_in[0];
    const float* w_qkv  = (const float*)d_in[1];
    const float* w_proj = (const float*)d_in[2];
    const float* b_proj = (const float*)d_in[3];
    float* out = (float*)d_out;

    const size_t qkv_elems = (size_t)B_ * H_ * N_ * D_;   // 4,194,304
    bf16* q_ws  = (bf16*)d_ws;
    bf16* kt_ws = q_ws + qkv_elems;                       // fragment-tiled K
    f16*  vt_ws = (f16*)(kt_ws + qkv_elems);              // V^T row-major f16
    bf16* o_ws  = (bf16*)(vt_ws + qkv_elems);
    bf16* x_bf  = o_ws  + qkv_elems;
    bf16* wq_bf = x_bf  + (size_t)B_ * N_ * C_;
    bf16* wp_bf = wq_bf + (size_t)3 * C_ * C_;

    cast_bf16    <<<2176, 256, 0, stream>>>(x, w_qkv, w_proj, x_bf, wq_bf, wp_bf);
    qkv_fast     <<<3072, 256, 0, stream>>>(x_bf, wq_bf, q_ws, kt_ws, vt_ws);
    attn         <<< 512, 256, 0, stream>>>(q_ws, kt_ws, vt_ws, o_ws);
    out_proj_fast<<<1024, 256, 0, stream>>>(o_ws, wp_bf, b_proj, out);
}

// Round 9
// 186.779 us; speedup vs baseline: 1.6138x; 1.5223x over previous
//
#include <hip/hip_runtime.h>
#include <hip/hip_bf16.h>

typedef __hip_bfloat16 bf16;
typedef _Float16 f16;
typedef __attribute__((ext_vector_type(8))) short bf16x8;
typedef __attribute__((ext_vector_type(8))) _Float16 f16x8;
typedef __attribute__((ext_vector_type(2))) _Float16 f16x2;
typedef __attribute__((ext_vector_type(4))) float f32x4;
typedef __attribute__((ext_vector_type(4))) unsigned int u32x4;
typedef __attribute__((ext_vector_type(2))) unsigned int u32x2;

#define B_ 4
#define N_ 4096
#define C_ 256
#define H_ 4
#define D_ 64
#define KLN 0.18033688011112042f   /* 0.125 * log2(e): folded into Q */

#if __has_builtin(__builtin_amdgcn_exp2f)
#define EXP2(x) __builtin_amdgcn_exp2f(x)
#else
#define EXP2(x) exp2f(x)
#endif
#if __has_builtin(__builtin_amdgcn_rcpf)
#define RCP(x) __builtin_amdgcn_rcpf(x)
#else
#define RCP(x) (1.0f / (x))
#endif

// direct global->LDS DMA, 16B per lane. LDS dest = wave-uniform base + lane*16.
__device__ inline void load_lds16(const void* g, void* l) {
#if __has_builtin(__builtin_amdgcn_global_load_lds)
    __builtin_amdgcn_global_load_lds(
        (const __attribute__((address_space(1))) unsigned int*)g,
        (__attribute__((address_space(3))) unsigned int*)l, 16, 0, 0);
#else
    int ln = __lane_id();
    ((u32x4*)l)[ln] = *((const u32x4*)g);
#endif
}

// two fp32 -> packed bf16 pair (round-half-up)
__device__ inline unsigned int pk2(float a, float b) {
    unsigned int ua = __builtin_bit_cast(unsigned int, a) + 0x8000u;
    unsigned int ub = __builtin_bit_cast(unsigned int, b) + 0x8000u;
    return (ua >> 16) | (ub & 0xffff0000u);
}
// two fp32 -> packed f16 pair (single v_cvt_pkrtz_f16_f32)
__device__ inline unsigned int pkh2(float a, float b) {
#if __has_builtin(__builtin_amdgcn_cvt_pkrtz)
    return __builtin_bit_cast(unsigned int, __builtin_amdgcn_cvt_pkrtz(a, b));
#else
    f16x2 h = { (f16)a, (f16)b };
    return __builtin_bit_cast(unsigned int, h);
#endif
}

// ---------------------------------------------------------------------------
// Prep: cast x, w_qkv, w_proj fp32 -> bf16 (memory-bound).
// ---------------------------------------------------------------------------
__global__ __launch_bounds__(256) void cast_bf16(const float* __restrict__ x,
                                                 const float* __restrict__ wq,
                                                 const float* __restrict__ wp,
                                                 bf16* __restrict__ xb,
                                                 bf16* __restrict__ wqb,
                                                 bf16* __restrict__ wpb)
{
    int bid = blockIdx.x;
    const float* s; bf16* d; int base;
    if (bid < 2048)      { s = x;  d = xb;  base = bid * 2048; }
    else if (bid < 2144) { s = wq; d = wqb; base = (bid - 2048) * 2048; }
    else                 { s = wp; d = wpb; base = (bid - 2144) * 2048; }
    int i = base + threadIdx.x * 8;
    f32x4 a = *reinterpret_cast<const f32x4*>(s + i);
    f32x4 b = *reinterpret_cast<const f32x4*>(s + i + 4);
    u32x4 o;
    o.x = pk2(a[0], a[1]); o.y = pk2(a[2], a[3]);
    o.z = pk2(b[0], b[1]); o.w = pk2(b[2], b[3]);
    *reinterpret_cast<u32x4*>(d + i) = o;
}

// ---------------------------------------------------------------------------
// QKV projection, bf16 in, W staged in LDS.
// Q -> row-major [B,H,N,D], pre-scaled by KLN.
// K -> FRAGMENT-TILED: one coalesced b128/lane per MFMA fragment.
// V -> transposed row-major [B,H,D,N] f16 (staged via DMA in attn).
// ---------------------------------------------------------------------------
__global__ __launch_bounds__(256, 2) void qkv_fast(const bf16* __restrict__ x,
                                                   const bf16* __restrict__ w,
                                                   bf16* __restrict__ qw,
                                                   bf16* __restrict__ kw,
                                                   f16* __restrict__ vtw)
{
    __shared__ short w_s[64][264];
    const int tid  = threadIdx.x;
    const int lane = tid & 63;
    const int wav  = tid >> 6;
    const int quad = lane >> 4;
    const int l16  = lane & 15;
    const int mt = blockIdx.x / 12, nb = blockIdx.x % 12;
    const int m0 = mt * 64, n0 = nb * 64;

    {
        const int row = tid >> 2, cb = (tid & 3) * 64;
        const bf16* src = w + (size_t)(n0 + row) * C_ + cb;
#pragma unroll
        for (int i = 0; i < 8; ++i)
            *reinterpret_cast<bf16x8*>(&w_s[row][cb + i * 8]) =
                *reinterpret_cast<const bf16x8*>(src + i * 8);
    }
    __syncthreads();

    f32x4 acc[4] = {{0,0,0,0},{0,0,0,0},{0,0,0,0},{0,0,0,0}};
    const bf16* xrow = x + (size_t)(m0 + wav * 16 + l16) * C_ + quad * 8;
#pragma unroll
    for (int k0 = 0; k0 < C_; k0 += 32) {
        bf16x8 a = *reinterpret_cast<const bf16x8*>(xrow + k0);
#pragma unroll
        for (int nt = 0; nt < 4; ++nt) {
            bf16x8 b = *reinterpret_cast<const bf16x8*>(&w_s[nt * 16 + l16][k0 + quad * 8]);
            acc[nt] = __builtin_amdgcn_mfma_f32_16x16x32_bf16(a, b, acc[nt], 0, 0, 0);
        }
    }

    const int bb = m0 >> 12;
    const int nbase = (m0 + wav * 16) & (N_ - 1);
    if (nb < 4) {                            // Q row-major, scaled
        const int h = nb;
#pragma unroll
        for (int nt = 0; nt < 4; ++nt)
#pragma unroll
            for (int r = 0; r < 4; ++r) {
                int n = nbase + quad * 4 + r, d = nt * 16 + l16;
                qw[(((size_t)bb * H_ + h) * N_ + n) * D_ + d] =
                    __float2bfloat16(acc[nt][r] * KLN);
            }
    } else if (nb < 8) {                     // K fragment-tiled
        const int h = nb - 4;
        bf16* kb_ = kw + (size_t)(bb * H_ + h) * (N_ / 16) * 1024;
        const int jblk = nbase >> 4;
#pragma unroll
        for (int nt = 0; nt < 4; ++nt) {
            const int base = jblk * 1024 + (nt >> 1) * 512 +
                             (((nt * 2) + (l16 >> 3)) & 3) * 128 + (l16 & 7);
#pragma unroll
            for (int r = 0; r < 4; ++r)
                kb_[base + (quad * 4 + r) * 8] = __float2bfloat16(acc[nt][r]);
        }
    } else {                                 // V transposed row-major, f16
        const int h = nb - 8;
#pragma unroll
        for (int nt = 0; nt < 4; ++nt) {
            int d = nt * 16 + l16;
            u32x2 wv;
            wv.x = pkh2(acc[nt][0], acc[nt][1]);
            wv.y = pkh2(acc[nt][2], acc[nt][3]);
            *reinterpret_cast<u32x2*>(
                vtw + (((size_t)bb * H_ + h) * D_ + d) * N_ + nbase + quad * 4) = wv;
        }
    }
}

// ---------------------------------------------------------------------------
// Flash attention v6b: round-8 structure at __launch_bounds__(256,2).
// (256,3) capped the unified register file at ~170/wave -> kc/qb spilled to
// scratch (WRITE_SIZE 255 MB). At (256,2) the budget is 256/wave: ~120 arch
// + 80 acc fits with headroom. 2 blocks/CU (8 waves), as in round 6.
// K: register-direct single-buffered from the fragment-tiled layout.
// V: global_load_lds into XOR-swizzled LDS. P: same-wave LDS round-trip.
// l: VALU accumulation. LDS 52 KB.
// ---------------------------------------------------------------------------
__global__ __launch_bounds__(256, 2) void attn(const bf16* __restrict__ q,
                                               const bf16* __restrict__ kt,
                                               const f16* __restrict__ vt,
                                               bf16* __restrict__ o)
{
    __shared__ f16          v_s[2][64 * 64];     // [jh][d*64 + slot*8], 16 KB
    __shared__ unsigned int p_s[4][64 * 36];     // per-wave P^T; merge buf; 36 KB

    const int tid  = threadIdx.x;
    const int lane = tid & 63;
    const int wav  = tid >> 6;
    const int quad = lane >> 4;
    const int l16  = lane & 15;
    const int l8   = l16 & 7;
    const int sub  = wav & 1;        // q-subtile (64 rows)
    const int jh   = wav >> 1;       // j-half
    const int bh = (blockIdx.x & 7) | (((blockIdx.x >> 3) & 1) << 3);  // XCD-grouped
    const int qt = blockIdx.x >> 4;  // 0..31
    const int bb = bh >> 2, h = bh & 3;

    const bf16* qp  = q  + (size_t)bh * N_ * D_;
    const bf16* ktp = kt + (size_t)bh * (N_ / 16) * 1024 + lane * 8;
    const f16*  vp  = vt + (size_t)bh * D_ * N_;

    const int qbase = qt * 128 + sub * 64;
    bf16x8 qb[4][2];
#pragma unroll
    for (int qg = 0; qg < 4; ++qg)
#pragma unroll
        for (int ks = 0; ks < 2; ++ks)
            qb[qg][ks] = *reinterpret_cast<const bf16x8*>(
                qp + (size_t)(qbase + qg * 16 + l16) * D_ + ks * 32 + quad * 8);

    // V staging geometry (XOR swizzle: slot = chunk ^ (row&7))
    const int ri = lane >> 3;
    const int ci = lane & 7;
    const int gc = ci ^ ri;

    f32x4 oacc[4][4];
#pragma unroll
    for (int qg = 0; qg < 4; ++qg)
#pragma unroll
        for (int dt = 0; dt < 4; ++dt) oacc[qg][dt] = (f32x4){0,0,0,0};
    float lsum[4] = {0.f, 0.f, 0.f, 0.f};

    for (int t = 0; t < 32; ++t) {
        const int j0 = jh * 2048 + t * 64;

        // K fragments for this tile: global->reg, issued BEFORE the barriers
        // (latency overlaps the barrier wait + V-DMA drain).
        bf16x8 kc[4][2];
        const int jbt = j0 >> 4;
#pragma unroll
        for (int nt = 0; nt < 4; ++nt)
#pragma unroll
            for (int ks = 0; ks < 2; ++ks)
                kc[nt][ks] = *reinterpret_cast<const bf16x8*>(
                    ktp + (size_t)(jbt + nt) * 1024 + ks * 512);

        __syncthreads();                        // prev tile's v_s reads done
#pragma unroll
        for (int g = 0; g < 4; ++g) {           // each wave stages 32 d-rows of V
            const int rl_ = sub * 32 + g * 8;
            load_lds16(vp + (size_t)(rl_ + ri) * N_ + j0 + gc * 8, &v_s[jh][rl_ * 64]);
        }
        __syncthreads();                        // vmcnt(0): v_s staged, kc arrived

        // S^T = K·Q^T per q-group; p = exp2(s); l += p; pack f16 -> p_s
#pragma unroll
        for (int qg = 0; qg < 4; ++qg) {
            f32x4 s[4] = {{0,0,0,0},{0,0,0,0},{0,0,0,0},{0,0,0,0}};
#pragma unroll
            for (int nt = 0; nt < 4; ++nt) {
                s[nt] = __builtin_amdgcn_mfma_f32_16x16x32_bf16(kc[nt][0], qb[qg][0], s[nt], 0, 0, 0);
                s[nt] = __builtin_amdgcn_mfma_f32_16x16x32_bf16(kc[nt][1], qb[qg][1], s[nt], 0, 0, 0);
            }
            unsigned int* prow = &p_s[wav][(qg * 16 + l16) * 36];
            float lq = 0.f;
#pragma unroll
            for (int nt = 0; nt < 4; ++nt) {
                float p0 = EXP2(s[nt][0]);
                float p1 = EXP2(s[nt][1]);
                float p2 = EXP2(s[nt][2]);
                float p3 = EXP2(s[nt][3]);
                lq += (p0 + p1) + (p2 + p3);
                u32x2 w2 = { pkh2(p0, p1), pkh2(p2, p3) };
                *reinterpret_cast<u32x2*>(prow + nt * 8 + quad * 2) = w2;
            }
            lsum[qg] += lq;
        }
        asm volatile("" ::: "memory");   // pin same-wave DS write->read order

        // O^T += V^T·P^T
#pragma unroll
        for (int ks = 0; ks < 2; ++ks) {
            f16x8 pb[4];
#pragma unroll
            for (int qg = 0; qg < 4; ++qg) {
                u32x4 pw = *reinterpret_cast<const u32x4*>(
                    &p_s[wav][(qg * 16 + l16) * 36 + ks * 16 + quad * 4]);
                pb[qg] = __builtin_bit_cast(f16x8, pw);
            }
#pragma unroll
            for (int dt = 0; dt < 4; ++dt) {
                f16x8 va = *reinterpret_cast<const f16x8*>(
                    &v_s[jh][(dt * 16 + l16) * 64 + (((ks << 2) + quad) ^ l8) * 8]);
#pragma unroll
                for (int qg = 0; qg < 4; ++qg)
                    oacc[qg][dt] = __builtin_amdgcn_mfma_f32_16x16x32_f16(va, pb[qg], oacc[qg][dt], 0, 0, 0);
            }
        }
    }

    // cross-quad completion of l
#pragma unroll
    for (int qg = 0; qg < 4; ++qg) {
        lsum[qg] += __shfl_xor(lsum[qg], 16, 64);
        lsum[qg] += __shfl_xor(lsum[qg], 32, 64);
    }

    // ---- merge j-halves (exact: O and l add), then normalize + store ----
    __syncthreads();
    float* mrg = reinterpret_cast<float*>(p_s);
    if (jh == 1) {
        float* dst = mrg + (sub * 64 + lane) * 68;
#pragma unroll
        for (int qg = 0; qg < 4; ++qg) {
#pragma unroll
            for (int dt = 0; dt < 4; ++dt)
#pragma unroll
                for (int e = 0; e < 4; ++e)
                    dst[qg * 17 + dt * 4 + e] = oacc[qg][dt][e];
            dst[qg * 17 + 16] = lsum[qg];
        }
    }
    __syncthreads();
    if (jh == 0) {
        const float* src = mrg + (sub * 64 + lane) * 68;
#pragma unroll
        for (int qg = 0; qg < 4; ++qg) {
            float rl = RCP(lsum[qg] + src[qg * 17 + 16]);
            const size_t obase = ((size_t)bb * N_ + qbase + qg * 16 + l16) * C_ + h * D_;
#pragma unroll
            for (int dt = 0; dt < 4; ++dt) {
                float v0 = (oacc[qg][dt][0] + src[qg * 17 + dt * 4 + 0]) * rl;
                float v1 = (oacc[qg][dt][1] + src[qg * 17 + dt * 4 + 1]) * rl;
                float v2 = (oacc[qg][dt][2] + src[qg * 17 + dt * 4 + 2]) * rl;
                float v3 = (oacc[qg][dt][3] + src[qg * 17 + dt * 4 + 3]) * rl;
                u32x2 wv = { pk2(v0, v1), pk2(v2, v3) };
                *reinterpret_cast<u32x2*>(o + obase + dt * 16 + quad * 4) = wv;
            }
        }
    }
}

// ---------------------------------------------------------------------------
// Output projection with W (bf16) staged in LDS; fp32 out + bias.
// ---------------------------------------------------------------------------
__global__ __launch_bounds__(256, 2) void out_proj_fast(const bf16* __restrict__ ov,
                                                        const bf16* __restrict__ w,
                                                        const float* __restrict__ bias,
                                                        float* __restrict__ out)
{
    __shared__ short w_s[64][264];
    const int tid  = threadIdx.x;
    const int lane = tid & 63;
    const int wav  = tid >> 6;
    const int quad = lane >> 4;
    const int l16  = lane & 15;
    const int m0 = (blockIdx.x >> 2) * 64;
    const int n0 = (blockIdx.x & 3) * 64;

    {
        const int row = tid >> 2, cb = (tid & 3) * 64;
        const bf16* src = w + (size_t)(n0 + row) * C_ + cb;
#pragma unroll
        for (int i = 0; i < 8; ++i)
            *reinterpret_cast<bf16x8*>(&w_s[row][cb + i * 8]) =
                *reinterpret_cast<const bf16x8*>(src + i * 8);
    }
    __syncthreads();

    f32x4 acc[4] = {{0,0,0,0},{0,0,0,0},{0,0,0,0},{0,0,0,0}};
    const bf16* orow = ov + (size_t)(m0 + wav * 16 + l16) * C_ + quad * 8;
#pragma unroll
    for (int k0 = 0; k0 < C_; k0 += 32) {
        bf16x8 a = *reinterpret_cast<const bf16x8*>(orow + k0);
#pragma unroll
        for (int nt = 0; nt < 4; ++nt) {
            bf16x8 b = *reinterpret_cast<const bf16x8*>(&w_s[nt * 16 + l16][k0 + quad * 8]);
            acc[nt] = __builtin_amdgcn_mfma_f32_16x16x32_bf16(a, b, acc[nt], 0, 0, 0);
        }
    }
#pragma unroll
    for (int nt = 0; nt < 4; ++nt)
#pragma unroll
        for (int r = 0; r < 4; ++r) {
            int m  = m0 + wav * 16 + quad * 4 + r;
            int oc = n0 + nt * 16 + l16;
            out[(size_t)m * C_ + oc] = acc[nt][r] + bias[oc];
        }
}

extern "C" void kernel_launch(void* const* d_in, const int* in_sizes, int n_in,
                              void* d_out, int out_size, void* d_ws, size_t ws_size,
                              hipStream_t stream) {
    const float* x      = (const float*)d_in[0];
    const float* w_qkv  = (const float*)d_in[1];
    const float* w_proj = (const float*)d_in[2];
    const float* b_proj = (const float*)d_in[3];
    float* out = (float*)d_out;

    const size_t qkv_elems = (size_t)B_ * H_ * N_ * D_;   // 4,194,304
    bf16* q_ws  = (bf16*)d_ws;
    bf16* kt_ws = q_ws + qkv_elems;                       // fragment-tiled K
    f16*  vt_ws = (f16*)(kt_ws + qkv_elems);              // V^T row-major f16
    bf16* o_ws  = (bf16*)(vt_ws + qkv_elems);
    bf16* x_bf  = o_ws  + qkv_elems;
    bf16* wq_bf = x_bf  + (size_t)B_ * N_ * C_;
    bf16* wp_bf = wq_bf + (size_t)3 * C_ * C_;

    cast_bf16    <<<2176, 256, 0, stream>>>(x, w_qkv, w_proj, x_bf, wq_bf, wp_bf);
    qkv_fast     <<<3072, 256, 0, stream>>>(x_bf, wq_bf, q_ws, kt_ws, vt_ws);
    attn         <<< 512, 256, 0, stream>>>(q_ws, kt_ws, vt_ws, o_ws);
    out_proj_fast<<<1024, 256, 0, stream>>>(o_ws, wp_bf, b_proj, out);
}